// Round 15
// baseline (138.750 us; speedup 1.0000x reference)
//
#include <hip/hip_runtime.h>
#include <stdint.h>
#include <math.h>

#define NQ    2562
#define NQ4   (4 * NQ)        // 10248 query-instances
#define MPTS  16384
#define NRUNS 8192            // 2048 blocks x 4 waves, 8 blocks/CU -> full residency
#define CAP   320             // stack cap: 63 leftover + 256 worst burst

#define YSQ_BYTES   ((size_t)(4 * MPTS) * sizeof(float))
#define PART_BYTES  ((size_t)NQ4 * 2 * 16 * sizeof(unsigned long long))

// run r covers units [start(r), start(r+1)), unit u = (q,tile) = (u>>6, u&63)
// start(r) = floor(r*1281/16) = 80r + r/16 ; inverse: run_of(u) = (16u+15)/1281
__device__ __forceinline__ int run_start(int r) { return 80 * r + (r >> 4); }
__device__ __forceinline__ int run_of(int u)   { return (16 * u + 15) / 1281; }

// ---------------------------------------------------------------------------
// Kernel 1: copy inputs [N,3] into output columns 0..2 of [N,15]
// ---------------------------------------------------------------------------
__global__ __launch_bounds__(256)
void passthrough_kernel(const float* __restrict__ inp, float* __restrict__ out) {
    int gid = blockIdx.x * 256 + threadIdx.x;
    if (gid < NQ * 3) {
        int n = gid / 3, c = gid - n * 3;
        out[n * 15 + c] = inp[gid];
    }
}

// key = (x^2sum + y^2sum) - 2*x.y  mirroring numpy association (left-assoc _rn,
// fma dot with pre-doubled query coords).
__device__ __forceinline__ float sqsum3(float y0, float y1, float y2) {
    return __fadd_rn(__fadd_rn(__fmul_rn(y0, y0), __fmul_rn(y1, y1)),
                     __fmul_rn(y2, y2));
}
__device__ __forceinline__ float keyf(float xs, float a2, float b2, float c2,
                                      float y0, float y1, float y2, float ysq) {
    float u = fmaf(c2, y2, fmaf(b2, y1, __fmul_rn(a2, y0)));
    return __fsub_rn(__fadd_rn(xs, ysq), u);
}
__device__ __forceinline__ unsigned long long packkey(float k, int m) {
    uint32_t kb = __float_as_uint(k);
    kb ^= (uint32_t)((int32_t)kb >> 31) | 0x80000000u;  // monotonic total-order map
    return ((unsigned long long)kb << 32) | (unsigned)m;
}
__device__ __forceinline__ float unmapkey(unsigned long long pk) {
    uint32_t kb = (uint32_t)(pk >> 32);
    return __uint_as_float((kb & 0x80000000u) ? (kb ^ 0x80000000u) : ~kb);
}
__device__ __forceinline__ int prefix_lt(unsigned long long m) {
    return __builtin_amdgcn_mbcnt_hi((unsigned)(m >> 32),
           __builtin_amdgcn_mbcnt_lo((unsigned)m, 0u));
}

// 64-lane bitonic sort ascending.
__device__ __forceinline__ unsigned long long sort64(unsigned long long v, int lane) {
#pragma unroll
    for (int k = 2; k <= 64; k <<= 1) {
#pragma unroll
        for (int j = k >> 1; j > 0; j >>= 1) {
            unsigned long long p = __shfl_xor(v, j);
            bool up = ((lane & k) == 0) == ((lane & j) == 0);
            bool sw = up ? (p < v) : (v < p);
            v = sw ? p : v;
        }
    }
    return v;
}

// Fold stack chunks (packed u64, LDS-only) into sorted t16 (LDS). No barriers.
__device__ __forceinline__ float rebuild_q(unsigned long long* t16p,
                                           unsigned long long* S, int& cnt,
                                           int lane, bool fin) {
    int c = cnt;
    int full = c >> 6, rem = c & 63;
    int rounds = full + ((fin && rem) ? 1 : 0);
    unsigned long long v = ~0ULL;
    for (int rd = 0; rd < rounds; ++rd) {
        int i = (rd << 6) + lane;
        unsigned long long pk = (i < c) ? S[i] : ~0ULL;
        pk = sort64(pk, lane);             // asc across lanes
        unsigned long long bsw = __shfl(pk, (31 - lane) & 63);
        v = (lane < 16) ? t16p[lane & 15] : (lane < 32) ? bsw : ~0ULL;
#pragma unroll
        for (int j = 16; j > 0; j >>= 1) {
            unsigned long long p2 = __shfl_xor(v, j);
            bool keepmin = (lane & j) == 0;
            bool less = p2 < v;
            v = (keepmin == less) ? p2 : v;
        }
        if (lane < 16) t16p[lane] = v;
    }
    if (!fin) {
        if (lane < rem) S[lane] = S[(full << 6) + lane];   // disjoint (full>=1)
        cnt = rem;
    } else {
        cnt = 0;
    }
    return unmapkey(__shfl(v, 15));
}

// ---------------------------------------------------------------------------
// Kernel 1b: precompute ysq[pc][m] = ||y||^2 with the exact stream formula
// ---------------------------------------------------------------------------
__global__ __launch_bounds__(256)
void ysq_kernel(const float* __restrict__ pc0, const float* __restrict__ pc1,
                const float* __restrict__ pc2, const float* __restrict__ pc3,
                float* __restrict__ ysq) {
    int gid = blockIdx.x * 256 + threadIdx.x;   // 0 .. 4*MPTS-1
    int pc = gid >> 14, m = gid & (MPTS - 1);
    const float* P = (pc == 0) ? pc0 : (pc == 1) ? pc1 : (pc == 2) ? pc2 : pc3;
    ysq[gid] = sqsum3(P[m], P[MPTS + m], P[2 * MPTS + m]);
}

__device__ __forceinline__ const float* selpc(int pc, const float* p0,
                                              const float* p1, const float* p2,
                                              const float* p3) {
    return (pc == 0) ? p0 : (pc == 1) ? p1 : (pc == 2) ? p2 : p3;
}

// ---------------------------------------------------------------------------
// Kernel 2: 2048 blocks x 256 thr (4 waves). Wave = one run of 80-81
// (query,tile) units, processed per query-segment with the proven
// tau-gate + u64-stack + sort/merge fold machinery. Each finalized segment
// writes its exact sorted top-16 (packed u64) to part[(q*2+slot)*16 ..].
// slot = 1 iff this run starts inside query q. No barriers, no cross-wave LDS.
// ---------------------------------------------------------------------------
__global__ __launch_bounds__(256)
void knn_runs(const float* __restrict__ inp,
              const float* __restrict__ pc0, const float* __restrict__ pc1,
              const float* __restrict__ pc2, const float* __restrict__ pc3,
              const float* __restrict__ ysq,
              unsigned long long* __restrict__ part) {
    const int wid  = threadIdx.x >> 6;
    const int lane = threadIdx.x & 63;
    const int run  = blockIdx.x * 4 + wid;

    int       u    = run_start(run);
    const int su   = u;
    const int uend = run_start(run + 1);

    __shared__ unsigned long long stk_sh[4][CAP];
    __shared__ unsigned long long t16_sh[4][16];
    unsigned long long* S = stk_sh[wid];
    unsigned long long* T = t16_sh[wid];

    int q  = u >> 6, tl = u & 63;
    int pc = q / NQ;
    int n  = q - pc * NQ;
    const float* __restrict__ P = selpc(pc, pc0, pc1, pc2, pc3);
    const float* __restrict__ Q = ysq + pc * MPTS;

    while (u < uend) {
        // ---- segment of query q: tiles [tl, tl+seglen) ----
        int seglen = 64 - tl;
        { int rem = uend - u; if (seglen > rem) seglen = rem; }

        float x0 = inp[n * 3 + 0];
        float x1 = inp[n * 3 + 1];
        float x2 = inp[n * 3 + 2];
        float A2 = 2.0f * x0, B2 = 2.0f * x1, C2 = 2.0f * x2;
        float XS = sqsum3(x0, x1, x2);
        if (lane < 16) T[lane] = ~0ULL;
        float tau = 0.0f;
        int   cnt = 0;                       // wave-uniform -> SGPR

        for (int i = 0; i < seglen; ++i) {
            const int t    = tl + i;
            const int mofs = (t << 8) + (lane << 2);
            float4 xv = *(const float4*)(P + mofs);
            float4 yv = *(const float4*)(P + MPTS + mofs);
            float4 zv = *(const float4*)(P + 2 * MPTS + mofs);
            float4 qv = *(const float4*)(Q + mofs);

            float k0 = keyf(XS, A2, B2, C2, xv.x, yv.x, zv.x, qv.x);
            float k1 = keyf(XS, A2, B2, C2, xv.y, yv.y, zv.y, qv.y);
            float k2 = keyf(XS, A2, B2, C2, xv.z, yv.z, zv.z, qv.z);
            float k3 = keyf(XS, A2, B2, C2, xv.w, yv.w, zv.w, qv.w);
            float km = fminf(fminf(k0, k1), fminf(k2, k3));

            bool fire;
            if (i == 0) {
                // warm tau0: max over 16 groups (of 4 lanes) of group-mins;
                // >=16 distinct points <= tau0 -> valid upper bound of the
                // segment-so-far 16th at all times.
                float g = km;
                g = fminf(g, __shfl_xor(g, 1));
                g = fminf(g, __shfl_xor(g, 2));
                float m = g;
                m = fmaxf(m, __shfl_xor(m, 4));
                m = fmaxf(m, __shfl_xor(m, 8));
                m = fmaxf(m, __shfl_xor(m, 16));
                m = fmaxf(m, __shfl_xor(m, 32));
                tau = m;
                fire = true;
            } else {
                fire = (__ballot(km <= tau) != 0ULL);
            }

            if (fire) {
                unsigned long long b0 = __ballot(k0 <= tau);
                unsigned long long b1 = __ballot(k1 <= tau);
                unsigned long long b2 = __ballot(k2 <= tau);
                unsigned long long b3 = __ballot(k3 <= tau);
                int pre = prefix_lt(b0) + prefix_lt(b1) + prefix_lt(b2) + prefix_lt(b3);
                int tot = __popcll(b0) + __popcll(b1) + __popcll(b2) + __popcll(b3);
                int pos = cnt + pre;
                if (k0 <= tau) S[pos++] = packkey(k0, mofs + 0);
                if (k1 <= tau) S[pos++] = packkey(k1, mofs + 1);
                if (k2 <= tau) S[pos++] = packkey(k2, mofs + 2);
                if (k3 <= tau) S[pos++] = packkey(k3, mofs + 3);
                cnt += tot;
                if (cnt >= 64)               // headroom: 63 + 256 <= CAP-1
                    tau = rebuild_q(T, S, cnt, lane, false);
            }
        }

        if (cnt > 0) rebuild_q(T, S, cnt, lane, true);

        // write this segment's exact sorted top-16
        int slot = (su > (q << 6)) ? 1 : 0;
        if (lane < 16) part[(size_t)((q << 1) | slot) * 16 + lane] = T[lane];

        // advance to next query in run
        u += seglen; tl = 0;
        if (u < uend) {
            ++q; ++n;
            if (n == NQ) { n = 0; ++pc; P = selpc(pc, pc0, pc1, pc2, pc3);
                           Q = ysq + pc * MPTS; }
        }
    }
}

// ---------------------------------------------------------------------------
// Kernel 3: merge <=2 partials per query (bitonic 16+16), gather, mean, write.
// grid 1281 x 256: wave wv handles 2 queries (32-lane halves).
// ---------------------------------------------------------------------------
__global__ __launch_bounds__(256)
void merge_kernel(const float* __restrict__ pc0, const float* __restrict__ pc1,
                  const float* __restrict__ pc2, const float* __restrict__ pc3,
                  const unsigned long long* __restrict__ part,
                  float* __restrict__ out) {
    const int wv   = blockIdx.x * 4 + (threadIdx.x >> 6);   // 0..5123
    const int lane = threadIdx.x & 63;
    const int h    = lane >> 5;
    const int l32  = lane & 31;
    const int q    = wv * 2 + h;                            // 0..10247

    const int pc = q / NQ;
    const int n  = q - pc * NQ;
    const float* __restrict__ P = selpc(pc, pc0, pc1, pc2, pc3);

    const int u0 = q << 6;
    const bool two = (run_of(u0) != run_of(u0 + 63));

    unsigned long long v;
    if (l32 < 16) v = part[(size_t)(q << 1) * 16 + l32];
    else          v = two ? part[(size_t)((q << 1) | 1) * 16 + ((31 - l32) & 15)]
                          : ~0ULL;
    // bitonic merge: A asc (l32 0-15), B desc (l32 16-31)
#pragma unroll
    for (int j = 16; j > 0; j >>= 1) {
        unsigned long long p2 = __shfl_xor(v, j);
        bool keepmin = (l32 & j) == 0;
        bool less = p2 < v;
        v = (keepmin == less) ? p2 : v;
    }

    if (l32 < 16) {
        int idx = (int)(unsigned)v;
        float gx = P[idx];
        float gy = P[MPTS + idx];
        float gz = P[2 * MPTS + idx];
#pragma unroll
        for (int off = 8; off > 0; off >>= 1) {
            gx += __shfl_down(gx, off, 16);
            gy += __shfl_down(gy, off, 16);
            gz += __shfl_down(gz, off, 16);
        }
        if (l32 == 0) {
            float* o = out + n * 15 + 3 + 3 * pc;
            o[0] = gx * 0.0625f;
            o[1] = gy * 0.0625f;
            o[2] = gz * 0.0625f;
        }
    }
}

// ---------------------------------------------------------------------------
// Fallback (R13): one query per wave, full stream, in case d_ws is too small.
// ---------------------------------------------------------------------------
#define QPB   4
#define NBQ   641
#define NT    (MPTS / 256)
template <bool USE_YSQ>
__global__ __launch_bounds__(256)
void knn_fallback(const float* __restrict__ inp,
                  const float* __restrict__ pc0, const float* __restrict__ pc1,
                  const float* __restrict__ pc2, const float* __restrict__ pc3,
                  const float* __restrict__ ysq,
                  float* __restrict__ out) {
    const int b    = blockIdx.x;
    const int wid  = threadIdx.x >> 6;
    const int lane = threadIdx.x & 63;
    const int pc = b / NBQ;
    const int nb = b - pc * NBQ;
    const float* __restrict__ P = selpc(pc, pc0, pc1, pc2, pc3);

    __shared__ unsigned long long stk_sh[4][CAP];
    __shared__ unsigned long long t16_sh[4][16];
    if (lane < 16) t16_sh[wid][lane] = ~0ULL;

    float A2, B2, C2, XS;
    {
        int n = QPB * nb + wid;
        n = (n < NQ) ? n : (NQ - 1);
        float x0 = inp[n * 3 + 0], x1 = inp[n * 3 + 1], x2 = inp[n * 3 + 2];
        A2 = 2.0f * x0; B2 = 2.0f * x1; C2 = 2.0f * x2;
        XS = sqsum3(x0, x1, x2);
    }
    float tau = 0.0f;
    int   cnt = 0;
    const float* __restrict__ Pl = P + (lane << 2);
    const float* __restrict__ Ql = ysq + pc * MPTS + (lane << 2);
    unsigned long long* S = stk_sh[wid];
    unsigned long long* T = t16_sh[wid];

    for (int t = 0; t < NT; ++t) {
        const int mofs = (t << 8) + (lane << 2);
        float4 xv = *(const float4*)(Pl + (t << 8));
        float4 yv = *(const float4*)(Pl + MPTS + (t << 8));
        float4 zv = *(const float4*)(Pl + 2 * MPTS + (t << 8));
        float q0, q1, q2, q3;
        if (USE_YSQ) {
            float4 qv = *(const float4*)(Ql + (t << 8));
            q0 = qv.x; q1 = qv.y; q2 = qv.z; q3 = qv.w;
        } else {
            q0 = sqsum3(xv.x, yv.x, zv.x);
            q1 = sqsum3(xv.y, yv.y, zv.y);
            q2 = sqsum3(xv.z, yv.z, zv.z);
            q3 = sqsum3(xv.w, yv.w, zv.w);
        }
        float k0 = keyf(XS, A2, B2, C2, xv.x, yv.x, zv.x, q0);
        float k1 = keyf(XS, A2, B2, C2, xv.y, yv.y, zv.y, q1);
        float k2 = keyf(XS, A2, B2, C2, xv.z, yv.z, zv.z, q2);
        float k3 = keyf(XS, A2, B2, C2, xv.w, yv.w, zv.w, q3);
        float km = fminf(fminf(k0, k1), fminf(k2, k3));
        bool fire;
        if (t == 0) {
            float g = km;
            g = fminf(g, __shfl_xor(g, 1));
            g = fminf(g, __shfl_xor(g, 2));
            float m = g;
            m = fmaxf(m, __shfl_xor(m, 4));
            m = fmaxf(m, __shfl_xor(m, 8));
            m = fmaxf(m, __shfl_xor(m, 16));
            m = fmaxf(m, __shfl_xor(m, 32));
            tau = m; fire = true;
        } else {
            fire = (__ballot(km <= tau) != 0ULL);
        }
        if (fire) {
            unsigned long long b0 = __ballot(k0 <= tau);
            unsigned long long b1 = __ballot(k1 <= tau);
            unsigned long long b2 = __ballot(k2 <= tau);
            unsigned long long b3 = __ballot(k3 <= tau);
            int pre = prefix_lt(b0) + prefix_lt(b1) + prefix_lt(b2) + prefix_lt(b3);
            int tot = __popcll(b0) + __popcll(b1) + __popcll(b2) + __popcll(b3);
            int pos = cnt + pre;
            if (k0 <= tau) S[pos++] = packkey(k0, mofs + 0);
            if (k1 <= tau) S[pos++] = packkey(k1, mofs + 1);
            if (k2 <= tau) S[pos++] = packkey(k2, mofs + 2);
            if (k3 <= tau) S[pos++] = packkey(k3, mofs + 3);
            cnt += tot;
            if (cnt >= 64)
                tau = rebuild_q(T, S, cnt, lane, false);
        }
    }
    if (cnt > 0) rebuild_q(T, S, cnt, lane, true);

    if (lane < 16) {
        unsigned long long v = T[lane];
        int idx = (int)(unsigned)v;
        float gx = P[idx];
        float gy = P[MPTS + idx];
        float gz = P[2 * MPTS + idx];
#pragma unroll
        for (int off = 8; off > 0; off >>= 1) {
            gx += __shfl_down(gx, off, 16);
            gy += __shfl_down(gy, off, 16);
            gz += __shfl_down(gz, off, 16);
        }
        if (lane == 0) {
            int n = QPB * nb + wid;
            n = (n < NQ) ? n : (NQ - 1);
            float* o = out + n * 15 + 3 + 3 * pc;
            o[0] = gx * 0.0625f;
            o[1] = gy * 0.0625f;
            o[2] = gz * 0.0625f;
        }
    }
}

extern "C" void kernel_launch(void* const* d_in, const int* in_sizes, int n_in,
                              void* d_out, int out_size, void* d_ws, size_t ws_size,
                              hipStream_t stream) {
    const float* inp = (const float*)d_in[0];
    const float* pc0 = (const float*)d_in[1];
    const float* pc1 = (const float*)d_in[2];
    const float* pc2 = (const float*)d_in[3];
    const float* pc3 = (const float*)d_in[4];
    float* out = (float*)d_out;
    float* ysq = (float*)d_ws;
    unsigned long long* part =
        (unsigned long long*)((char*)d_ws + YSQ_BYTES);

    hipLaunchKernelGGL(passthrough_kernel, dim3((NQ * 3 + 255) / 256), dim3(256),
                       0, stream, inp, out);

    if (ws_size >= YSQ_BYTES + PART_BYTES) {
        hipLaunchKernelGGL(ysq_kernel, dim3(4 * MPTS / 256), dim3(256), 0, stream,
                           pc0, pc1, pc2, pc3, ysq);
        hipLaunchKernelGGL(knn_runs, dim3(NRUNS / 4), dim3(256), 0, stream,
                           inp, pc0, pc1, pc2, pc3, ysq, part);
        hipLaunchKernelGGL(merge_kernel, dim3(NQ4 / 8), dim3(256), 0, stream,
                           pc0, pc1, pc2, pc3, part, out);
    } else if (ws_size >= YSQ_BYTES) {
        hipLaunchKernelGGL(ysq_kernel, dim3(4 * MPTS / 256), dim3(256), 0, stream,
                           pc0, pc1, pc2, pc3, ysq);
        hipLaunchKernelGGL((knn_fallback<true>), dim3(4 * NBQ), dim3(256), 0,
                           stream, inp, pc0, pc1, pc2, pc3, ysq, out);
    } else {
        hipLaunchKernelGGL((knn_fallback<false>), dim3(4 * NBQ), dim3(256), 0,
                           stream, inp, pc0, pc1, pc2, pc3, ysq, out);
    }
}

// Round 16
// 104.329 us; speedup vs baseline: 1.3299x; 1.3299x over previous
//
#include <hip/hip_runtime.h>
#include <stdint.h>
#include <math.h>

#define NQ    2562
#define MPTS  16384
#define QPB   2            // queries per block = 2 waves x 1  (residency quantum!)
#define NBQ   1281         // NQ / QPB exactly (no tail)
#define NT    (MPTS / 256) // 64 stream iters per wave (full stream)
#define CAP   320          // stack cap per wave-query: 63 leftover + 256 worst burst

// ---------------------------------------------------------------------------
// Kernel 1: copy inputs [N,3] into output columns 0..2 of [N,15]
// ---------------------------------------------------------------------------
__global__ __launch_bounds__(256)
void passthrough_kernel(const float* __restrict__ inp, float* __restrict__ out) {
    int gid = blockIdx.x * 256 + threadIdx.x;
    if (gid < NQ * 3) {
        int n = gid / 3, c = gid - n * 3;
        out[n * 15 + c] = inp[gid];
    }
}

// key = (x^2sum + y^2sum) - 2*x.y  mirroring numpy association (left-assoc _rn,
// fma dot with pre-doubled query coords).
__device__ __forceinline__ float sqsum3(float y0, float y1, float y2) {
    return __fadd_rn(__fadd_rn(__fmul_rn(y0, y0), __fmul_rn(y1, y1)),
                     __fmul_rn(y2, y2));
}
__device__ __forceinline__ float keyf(float xs, float a2, float b2, float c2,
                                      float y0, float y1, float y2, float ysq) {
    float u = fmaf(c2, y2, fmaf(b2, y1, __fmul_rn(a2, y0)));
    return __fsub_rn(__fadd_rn(xs, ysq), u);
}
__device__ __forceinline__ unsigned long long packkey(float k, int m) {
    uint32_t kb = __float_as_uint(k);
    kb ^= (uint32_t)((int32_t)kb >> 31) | 0x80000000u;  // monotonic total-order map
    return ((unsigned long long)kb << 32) | (unsigned)m;
}
__device__ __forceinline__ float unmapkey(unsigned long long pk) {
    uint32_t kb = (uint32_t)(pk >> 32);
    return __uint_as_float((kb & 0x80000000u) ? (kb ^ 0x80000000u) : ~kb);
}
// popcount of mask over lanes < this lane (v_mbcnt pair)
__device__ __forceinline__ int prefix_lt(unsigned long long m) {
    return __builtin_amdgcn_mbcnt_hi((unsigned)(m >> 32),
           __builtin_amdgcn_mbcnt_lo((unsigned)m, 0u));
}

// 64-lane bitonic sort ascending.
__device__ __forceinline__ unsigned long long sort64(unsigned long long v, int lane) {
#pragma unroll
    for (int k = 2; k <= 64; k <<= 1) {
#pragma unroll
        for (int j = k >> 1; j > 0; j >>= 1) {
            unsigned long long p = __shfl_xor(v, j);
            bool up = ((lane & k) == 0) == ((lane & j) == 0);
            bool sw = up ? (p < v) : (v < p);
            v = sw ? p : v;
        }
    }
    return v;
}

// Fold stack chunks (packed u64, LDS-only) into sorted t16 (LDS). No barriers.
__device__ __forceinline__ float rebuild_q(unsigned long long* t16p,
                                           unsigned long long* S, int& cnt,
                                           int lane, bool fin) {
    int c = cnt;
    int full = c >> 6, rem = c & 63;
    int rounds = full + ((fin && rem) ? 1 : 0);
    unsigned long long v = ~0ULL;
    for (int rd = 0; rd < rounds; ++rd) {
        int i = (rd << 6) + lane;
        unsigned long long pk = (i < c) ? S[i] : ~0ULL;
        pk = sort64(pk, lane);             // asc across lanes
        unsigned long long bsw = __shfl(pk, (31 - lane) & 63);
        v = (lane < 16) ? t16p[lane & 15] : (lane < 32) ? bsw : ~0ULL;
#pragma unroll
        for (int j = 16; j > 0; j >>= 1) {
            unsigned long long p2 = __shfl_xor(v, j);
            bool keepmin = (lane & j) == 0;
            bool less = p2 < v;
            v = (keepmin == less) ? p2 : v;
        }
        if (lane < 16) t16p[lane] = v;
    }
    if (!fin) {
        if (lane < rem) S[lane] = S[(full << 6) + lane];   // disjoint (full>=1)
        cnt = rem;
    } else {
        cnt = 0;
    }
    return unmapkey(__shfl(v, 15));
}

// ---------------------------------------------------------------------------
// Kernel 1b: precompute ysq[pc][m] = ||y||^2 with the exact stream formula
// ---------------------------------------------------------------------------
__global__ __launch_bounds__(256)
void ysq_kernel(const float* __restrict__ pc0, const float* __restrict__ pc1,
                const float* __restrict__ pc2, const float* __restrict__ pc3,
                float* __restrict__ ysq) {
    int gid = blockIdx.x * 256 + threadIdx.x;   // 0 .. 4*MPTS-1
    int pc = gid >> 14, m = gid & (MPTS - 1);
    const float* P = (pc == 0) ? pc0 : (pc == 1) ? pc1 : (pc == 2) ? pc2 : pc3;
    ysq[gid] = sqsum3(P[m], P[MPTS + m], P[2 * MPTS + m]);
}

// ---------------------------------------------------------------------------
// Kernel 2: grid 4*NBQ x 128 (2 waves). Block b: pc = b/NBQ, wave wid owns
// query n = 2*(b%NBQ)+wid, streams ALL 16384 points (4/lane/iter, register
// prefetch). f32 tau gate + LDS stack of packed (key,idx) u64 + batched
// LDS-only folds. No cross-wave traffic, no __syncthreads. 2-wave blocks
// give a fine residency quantum: ~20 blocks/CU, 16 resident -> 1.25 rounds.
// ---------------------------------------------------------------------------
template <bool USE_YSQ>
__global__ __launch_bounds__(128)
void knn_kernel(const float* __restrict__ inp,
                const float* __restrict__ pc0, const float* __restrict__ pc1,
                const float* __restrict__ pc2, const float* __restrict__ pc3,
                const float* __restrict__ ysq,
                float* __restrict__ out) {
    const int b    = blockIdx.x;
    const int wid  = threadIdx.x >> 6;    // 0..1
    const int lane = threadIdx.x & 63;

    const int pc = b / NBQ;
    const int nb = b - pc * NBQ;
    const float* __restrict__ P = (pc == 0) ? pc0 : (pc == 1) ? pc1
                                : (pc == 2) ? pc2 : pc3;

    __shared__ unsigned long long stk_sh[2][CAP];
    __shared__ unsigned long long t16_sh[2][16];

    if (lane < 16) t16_sh[wid][lane] = ~0ULL;

    // this wave's query
    float A2, B2, C2, XS;
    const int n = QPB * nb + wid;          // always < NQ (2562 = 2*1281)
    {
        float x0 = inp[n * 3 + 0];
        float x1 = inp[n * 3 + 1];
        float x2 = inp[n * 3 + 2];
        A2 = 2.0f * x0;
        B2 = 2.0f * x1;
        C2 = 2.0f * x2;
        XS = sqsum3(x0, x1, x2);
    }
    float tau;
    int   cnt = 0;                         // wave-uniform -> SGPR

    const float* __restrict__ Pl = P + (lane << 2);
    const float* __restrict__ Ql = ysq + pc * MPTS + (lane << 2);

    // push one 256-pt tile (keys in registers); stores packed u64
    auto push_tile = [&](int mofs, float k0, float k1, float k2, float k3) {
        unsigned long long b0 = __ballot(k0 <= tau);
        unsigned long long b1 = __ballot(k1 <= tau);
        unsigned long long b2 = __ballot(k2 <= tau);
        unsigned long long b3 = __ballot(k3 <= tau);
        int pre = prefix_lt(b0) + prefix_lt(b1) + prefix_lt(b2) + prefix_lt(b3);
        int tot = __popcll(b0) + __popcll(b1) + __popcll(b2) + __popcll(b3);
        int pos = cnt + pre;
        unsigned long long* S = stk_sh[wid];
        if (k0 <= tau) S[pos++] = packkey(k0, mofs + 0);
        if (k1 <= tau) S[pos++] = packkey(k1, mofs + 1);
        if (k2 <= tau) S[pos++] = packkey(k2, mofs + 2);
        if (k3 <= tau) S[pos++] = packkey(k3, mofs + 3);
        cnt += tot;
        if (cnt >= 64)                     // headroom: 63 + 256 <= CAP-1
            tau = rebuild_q(t16_sh[wid], S, cnt, lane, false);
    };

    // ---- peeled t=0: warm tau + push ----
    {
        float4 ax = *(const float4*)(Pl);
        float4 ay = *(const float4*)(Pl + MPTS);
        float4 az = *(const float4*)(Pl + 2 * MPTS);
        float q0, q1, q2, q3;
        if (USE_YSQ) {
            float4 aq = *(const float4*)(Ql);
            q0 = aq.x; q1 = aq.y; q2 = aq.z; q3 = aq.w;
        } else {
            q0 = sqsum3(ax.x, ay.x, az.x);
            q1 = sqsum3(ax.y, ay.y, az.y);
            q2 = sqsum3(ax.z, ay.z, az.z);
            q3 = sqsum3(ax.w, ay.w, az.w);
        }
        float k0 = keyf(XS, A2, B2, C2, ax.x, ay.x, az.x, q0);
        float k1 = keyf(XS, A2, B2, C2, ax.y, ay.y, az.y, q1);
        float k2 = keyf(XS, A2, B2, C2, ax.z, ay.z, az.z, q2);
        float k3 = keyf(XS, A2, B2, C2, ax.w, ay.w, az.w, q3);
        float km = fminf(fminf(k0, k1), fminf(k2, k3));
        // warm tau0: max over 16 groups (of 4 lanes) of group-mins;
        // >=16 distinct points <= tau0 -> tau0 >= true 16th of these 256.
        float g = km;
        g = fminf(g, __shfl_xor(g, 1));
        g = fminf(g, __shfl_xor(g, 2));
        float m = g;
        m = fmaxf(m, __shfl_xor(m, 4));
        m = fmaxf(m, __shfl_xor(m, 8));
        m = fmaxf(m, __shfl_xor(m, 16));
        m = fmaxf(m, __shfl_xor(m, 32));
        tau = m;
        push_tile(lane << 2, k0, k1, k2, k3);
    }

    // prefetch t=1
    float4 cx = *(const float4*)(Pl + 256);
    float4 cy = *(const float4*)(Pl + MPTS + 256);
    float4 cz = *(const float4*)(Pl + 2 * MPTS + 256);
    float4 cq;
    if (USE_YSQ) cq = *(const float4*)(Ql + 256);

    for (int t = 1; t < NT; ++t) {
        const int tn = (t + 1 < NT) ? t + 1 : t;   // clamped prefetch (dup harmless)
        float4 nx = *(const float4*)(Pl + (tn << 8));
        float4 ny = *(const float4*)(Pl + MPTS + (tn << 8));
        float4 nz = *(const float4*)(Pl + 2 * MPTS + (tn << 8));
        float4 nq;
        if (USE_YSQ) nq = *(const float4*)(Ql + (tn << 8));

        const int mofs = (t << 8) + (lane << 2);
        float q0, q1, q2, q3;
        if (USE_YSQ) {
            q0 = cq.x; q1 = cq.y; q2 = cq.z; q3 = cq.w;
        } else {
            q0 = sqsum3(cx.x, cy.x, cz.x);
            q1 = sqsum3(cx.y, cy.y, cz.y);
            q2 = sqsum3(cx.z, cy.z, cz.z);
            q3 = sqsum3(cx.w, cy.w, cz.w);
        }
        float k0 = keyf(XS, A2, B2, C2, cx.x, cy.x, cz.x, q0);
        float k1 = keyf(XS, A2, B2, C2, cx.y, cy.y, cz.y, q1);
        float k2 = keyf(XS, A2, B2, C2, cx.z, cy.z, cz.z, q2);
        float k3 = keyf(XS, A2, B2, C2, cx.w, cy.w, cz.w, q3);
        float km = fminf(fminf(k0, k1), fminf(k2, k3));
        if (__ballot(km <= tau))
            push_tile(mofs, k0, k1, k2, k3);

        cx = nx; cy = ny; cz = nz;
        if (USE_YSQ) cq = nq;
    }

    // final fold of remaining stack entries
    if (cnt > 0)
        rebuild_q(t16_sh[wid], stk_sh[wid], cnt, lane, true);

    // tail: t16 sorted ascending; lanes 0..15 gather + mean
    if (lane < 16) {
        unsigned long long v = t16_sh[wid][lane];
        int idx = (int)(unsigned)v;
        float gx = P[idx];
        float gy = P[MPTS + idx];
        float gz = P[2 * MPTS + idx];
#pragma unroll
        for (int off = 8; off > 0; off >>= 1) {
            gx += __shfl_down(gx, off, 16);
            gy += __shfl_down(gy, off, 16);
            gz += __shfl_down(gz, off, 16);
        }
        if (lane == 0) {
            float* o = out + n * 15 + 3 + 3 * pc;
            o[0] = gx * 0.0625f;
            o[1] = gy * 0.0625f;
            o[2] = gz * 0.0625f;
        }
    }
}

extern "C" void kernel_launch(void* const* d_in, const int* in_sizes, int n_in,
                              void* d_out, int out_size, void* d_ws, size_t ws_size,
                              hipStream_t stream) {
    const float* inp = (const float*)d_in[0];
    const float* pc0 = (const float*)d_in[1];
    const float* pc1 = (const float*)d_in[2];
    const float* pc2 = (const float*)d_in[3];
    const float* pc3 = (const float*)d_in[4];
    float* out = (float*)d_out;
    float* ysq = (float*)d_ws;

    hipLaunchKernelGGL(passthrough_kernel, dim3((NQ * 3 + 255) / 256), dim3(256),
                       0, stream, inp, out);

    const bool use_ysq = (ws_size >= (size_t)(4 * MPTS * sizeof(float)));
    if (use_ysq) {
        hipLaunchKernelGGL(ysq_kernel, dim3(4 * MPTS / 256), dim3(256), 0, stream,
                           pc0, pc1, pc2, pc3, ysq);
        hipLaunchKernelGGL((knn_kernel<true>), dim3(4 * NBQ), dim3(128), 0, stream,
                           inp, pc0, pc1, pc2, pc3, ysq, out);
    } else {
        hipLaunchKernelGGL((knn_kernel<false>), dim3(4 * NBQ), dim3(128), 0, stream,
                           inp, pc0, pc1, pc2, pc3, ysq, out);
    }
}